// Round 1
// 435.980 us; speedup vs baseline: 1.0592x; 1.0592x over previous
//
#include <hip/hip_runtime.h>
#include <math.h>

// Problem constants (B=8, H=8, S=16384, Dv=64, d_k=1)
#define S_LEN 16384
#define DV    64
#define NBH   64             // B*H
#define NBLK  16             // stage-1 blocks per (b,h)
#define CHUNK (S_LEN / NBLK) // 1024 rows per stage-1 block

// ext_vector float4: supports scalar broadcast arithmetic and
// __builtin_nontemporal_load/store (HIP's struct float4 does not).
typedef float vf4 __attribute__((ext_vector_type(4)));

// out[b,h,s,e] = Q[s] * (sum_s K[s]*V[s,e]) / (||Q|| * ||K||)   per (b,h)

// ---------------- Stage 1: partial ktv + partial Q/K sumsq ----------------
// grid = NBH*NBLK blocks, 256 threads.
// Thread layout: e4 = tid & 15 (float4 column), sg = tid >> 4 (16 s-groups).
__global__ __launch_bounds__(256) void stage1_partial(
    const float* __restrict__ Q, const float* __restrict__ K,
    const float* __restrict__ V,
    float* __restrict__ pktv, float* __restrict__ pqk) {
    const int bh  = blockIdx.x >> 4;
    const int blk = blockIdx.x & 15;
    const int tid = threadIdx.x;
    const int e4  = tid & 15;
    const int sg  = tid >> 4;

    const float* Kb = K + (size_t)bh * S_LEN + blk * CHUNK;
    const float* Qb = Q + (size_t)bh * S_LEN + blk * CHUNK;
    const vf4*   Vb = (const vf4*)(V + (size_t)bh * S_LEN * DV)
                      + (size_t)blk * CHUNK * (DV / 4);

    vf4 acc = {0.f, 0.f, 0.f, 0.f};
    #pragma unroll 4
    for (int i = 0; i < CHUNK / 16; ++i) {
        const int s = i * 16 + sg;
        const float k = Kb[s];                                   // L1 broadcast
        const vf4 v = __builtin_nontemporal_load(Vb + s * (DV / 4) + e4);
        acc += k * v;                                            // coalesced 1 KiB/wave
    }

    // Q/K sum-of-squares partials: 256 float4 per chunk, one per thread.
    // (K chunk is L1/L2-hot from the loop above; Q chunk is the only new read.)
    const vf4 q4 = ((const vf4*)Qb)[tid];
    const vf4 k4 = ((const vf4*)Kb)[tid];
    float qss = q4.x * q4.x + q4.y * q4.y + q4.z * q4.z + q4.w * q4.w;
    float kss = k4.x * k4.x + k4.y * k4.y + k4.z * k4.z + k4.w * k4.w;
    #pragma unroll
    for (int off = 32; off > 0; off >>= 1) {
        qss += __shfl_down(qss, off);
        kss += __shfl_down(kss, off);
    }

    __shared__ vf4 red[16][16];   // [sg][e4]
    __shared__ float rq[4], rk[4];
    red[sg][e4] = acc;
    if ((tid & 63) == 0) { rq[tid >> 6] = qss; rk[tid >> 6] = kss; }
    __syncthreads();

    if (tid < DV) {               // tid = e in [0,64); conflict-free: consecutive floats
        const float* base = (const float*)red;
        float s = 0.f;
        #pragma unroll
        for (int p = 0; p < 16; ++p) s += base[p * DV + tid];
        pktv[((size_t)bh * NBLK + blk) * DV + tid] = s;
    }
    if (tid == 0) {
        pqk[(bh * NBLK + blk) * 2 + 0] = rq[0] + rq[1] + rq[2] + rq[3];
        pqk[(bh * NBLK + blk) * 2 + 1] = rk[0] + rk[1] + rk[2] + rk[3];
    }
}

// ---------------- Stage 2: tiny reduction + finalize fk table ----------------
// grid = NBH blocks, 64 threads (one wave). Reads only ~2 KB of partials per bh.
__global__ __launch_bounds__(64) void stage2_finalize(
    const float* __restrict__ pktv, const float* __restrict__ pqk,
    float* __restrict__ fk) {
    const int bh  = blockIdx.x;
    const int tid = threadIdx.x;   // 0..63 = e

    float qss = 0.f, kss = 0.f;
    if (tid < NBLK) {
        qss = pqk[(bh * NBLK + tid) * 2 + 0];
        kss = pqk[(bh * NBLK + tid) * 2 + 1];
    }
    #pragma unroll
    for (int off = 8; off > 0; off >>= 1) {   // sum lanes 0..15 into lane 0
        qss += __shfl_down(qss, off);
        kss += __shfl_down(kss, off);
    }
    const float inv = 1.0f / (sqrtf(__shfl(qss, 0)) * sqrtf(__shfl(kss, 0)));

    float s = 0.f;
    #pragma unroll
    for (int p = 0; p < NBLK; ++p)
        s += pktv[((size_t)bh * NBLK + p) * DV + tid];
    fk[bh * DV + tid] = s * inv;
}

// ---------------- Stage 3: rank-1 outer product write ----------------
// 2048 blocks (8/CU) x 256 threads, 32 float4 stores per thread (G11 pattern:
// the old 65536 one-store workgroups were dispatch-bound, not BW-bound).
// Stride-256 indexing keeps e4 = tid&15 loop-invariant -> fk hoisted to reg.
#define S3_BLOCKS 2048
#define F4_TOTAL  (NBH * S_LEN * (DV / 4))       // 16,777,216 float4
#define F4_PER_BLOCK (F4_TOTAL / S3_BLOCKS)      // 8192 (= 512 rows, one bh)

__global__ __launch_bounds__(256) void stage3_outer(
    const float* __restrict__ Q, const float* __restrict__ fk,
    vf4* __restrict__ out) {
    const size_t base = (size_t)blockIdx.x * F4_PER_BLOCK;
    const int tid = threadIdx.x;
    const int bh  = (int)(base >> 18);            // 262144 float4 per bh; 8192 | 262144
    const int e4  = tid & 15;
    const vf4 f = ((const vf4*)fk)[bh * 16 + e4]; // loop-invariant
    const float* Qb = Q + (size_t)bh * S_LEN;
    const int s0 = (int)((base >> 4) & (S_LEN - 1)) + (tid >> 4);

    #pragma unroll 8
    for (int t = 0; t < 32; ++t) {
        const float q = Qb[s0 + t * 16];          // L1 broadcast, 4 distinct/wave
        __builtin_nontemporal_store(q * f, out + base + t * 256 + tid);
    }
}

extern "C" void kernel_launch(void* const* d_in, const int* in_sizes, int n_in,
                              void* d_out, int out_size, void* d_ws, size_t ws_size,
                              hipStream_t stream) {
    const float* Q = (const float*)d_in[0];
    const float* K = (const float*)d_in[1];
    const float* V = (const float*)d_in[2];
    float* out = (float*)d_out;

    // Workspace layout:
    //   pktv: NBH*NBLK*DV floats (256 KB)  partial K^T V
    //   pqk : NBH*NBLK*2 floats            partial (qss, kss)
    //   fk  : NBH*DV floats                finalized ktv / (||Q||*||K||)
    float* pktv = (float*)d_ws;
    float* pqk  = pktv + (size_t)NBH * NBLK * DV;
    float* fk   = pqk + NBH * NBLK * 2;

    stage1_partial<<<NBH * NBLK, 256, 0, stream>>>(Q, K, V, pktv, pqk);
    stage2_finalize<<<NBH, 64, 0, stream>>>(pktv, pqk, fk);
    stage3_outer<<<S3_BLOCKS, 256, 0, stream>>>(Q, fk, (vf4*)out);
}